// Round 7
// baseline (65.229 us; speedup 1.0000x reference)
//
#include <hip/hip_runtime.h>
#include <math.h>

// (B,C,H,W) = (64,512,28,28)
#define NC    512
#define CST   784          // H*W floats
#define GP4   196          // float4 groups per image plane (784/4)
#define NG4   12544        // total float4 groups (64*196)
#define SEG   32           // channels per wave
#define NSEG  16           // waves per block
#define TPB   1024
#define NBLK  196          // NG4 / 64 lanes
#define GSZ   25690112

// ws: [0,8) double acc; [8,12) int ticket; memset 16B each launch

__global__ __launch_bounds__(TPB, 4) void k_fused(const float* __restrict__ x,
                                                  const float* __restrict__ w,
                                                  float* __restrict__ g,
                                                  double* __restrict__ acc,
                                                  int* __restrict__ ticket,
                                                  float* __restrict__ out) {
    const int lane = threadIdx.x & 63;
    const int s    = threadIdx.x >> 6;           // wave id = channel segment
    const int p4   = blockIdx.x * 64 + lane;     // float4 column-group id
    const int b    = p4 / GP4;
    const int g4   = p4 - b * GP4;
    const size_t base = (size_t)b * (NC * GP4) + g4;   // float4 index; +k*GP4 per channel
    const float4* X4 = (const float4*)x;
    float4*       G4 = (float4*)g;
    const int k0   = s * SEG;
    const int jend = (s == NSEG - 1) ? SEG - 1 : SEG;  // wave-uniform; skips k=511 in A

    __shared__ float  wl[NC];                    // wl[511] = 0
    __shared__ float4 sA[NSEG][64];
    __shared__ float4 sB[NSEG][64];
    __shared__ float  lpart[NSEG];

    if (threadIdx.x < NC)
        wl[threadIdx.x] = (threadIdx.x < NC - 1) ? w[threadIdx.x] : 0.f;
    __syncthreads();

    // ---- phase A: per-segment partials (1 KiB/wave vector loads) ----
    float4 xv = X4[base + (size_t)k0 * GP4];
    float4 pa = make_float4(0.f, 0.f, 0.f, 0.f);
    float4 pb = make_float4(0.f, 0.f, 0.f, 0.f);
    #pragma unroll 8
    for (int j = 0; j < jend; ++j) {
        const int k = k0 + j;
        const float4 xn = X4[base + (size_t)(k + 1) * GP4];
        const float wk = wl[k];
        pa.x = fmaf(xv.x, wk, pa.x); pa.y = fmaf(xv.y, wk, pa.y);
        pa.z = fmaf(xv.z, wk, pa.z); pa.w = fmaf(xv.w, wk, pa.w);
        pb.x = fmaf(xn.x, wk, pb.x); pb.y = fmaf(xn.y, wk, pb.y);
        pb.z = fmaf(xn.z, wk, pb.z); pb.w = fmaf(xn.w, wk, pb.w);
        xv = xn;
    }
    sA[s][lane] = pa;
    sB[s][lane] = pb;
    __syncthreads();

    // ---- g[k0] = sum_{t<s} A_t + sum_{t>=s} B_t ----
    float4 r = make_float4(0.f, 0.f, 0.f, 0.f);
    #pragma unroll
    for (int t = 0; t < NSEG; ++t) {
        const float4 v = (t < s) ? sA[t][lane] : sB[t][lane];
        r.x += v.x; r.y += v.y; r.z += v.z; r.w += v.w;
    }

    // ---- phase B: reload (L2/L3-hot), emit g, accumulate loss ----
    float4 xv2 = X4[base + (size_t)k0 * GP4];
    float4 la = make_float4(0.f, 0.f, 0.f, 0.f);
    #pragma unroll 8
    for (int j = 0; j < jend; ++j) {
        const int k = k0 + j;
        const float4 xn = X4[base + (size_t)(k + 1) * GP4];
        G4[base + (size_t)k * GP4] = r;
        const float dx = r.x - xv2.x, dy = r.y - xv2.y;
        const float dz = r.z - xv2.z, dw = r.w - xv2.w;
        la.x = fmaf(dx, dx, la.x); la.y = fmaf(dy, dy, la.y);
        la.z = fmaf(dz, dz, la.z); la.w = fmaf(dw, dw, la.w);
        const float wk = wl[k];
        r.x = fmaf(wk, xv2.x - xn.x, r.x); r.y = fmaf(wk, xv2.y - xn.y, r.y);
        r.z = fmaf(wk, xv2.z - xn.z, r.z); r.w = fmaf(wk, xv2.w - xn.w, r.w);
        xv2 = xn;
    }
    if (s == NSEG - 1) {   // channel 511 epilogue
        G4[base + (size_t)(NC - 1) * GP4] = r;
        const float dx = r.x - xv2.x, dy = r.y - xv2.y;
        const float dz = r.z - xv2.z, dw = r.w - xv2.w;
        la.x = fmaf(dx, dx, la.x); la.y = fmaf(dy, dy, la.y);
        la.z = fmaf(dz, dz, la.z); la.w = fmaf(dw, dw, la.w);
    }

    // ---- loss: wave reduce -> block reduce -> device atomic + ticket ----
    float ls = (la.x + la.y) + (la.z + la.w);
    #pragma unroll
    for (int off = 32; off; off >>= 1) ls += __shfl_down(ls, off, 64);
    if (lane == 0) lpart[s] = ls;
    __syncthreads();
    if (threadIdx.x == 0) {
        float t = 0.f;
        #pragma unroll
        for (int i = 0; i < NSEG; ++i) t += lpart[i];
        atomicAdd(acc, (double)t);               // device-scope
        __threadfence();
        const int my = atomicAdd(ticket, 1);
        if (my == NBLK - 1) {                    // all 196 acc-adds complete
            const double tot = __hip_atomic_load(acc, __ATOMIC_ACQUIRE,
                                                 __HIP_MEMORY_SCOPE_AGENT);
            out[0] = (float)(sqrt(tot) * 0.0025);
        }
    }
}

extern "C" void kernel_launch(void* const* d_in, const int* in_sizes, int n_in,
                              void* d_out, int out_size, void* d_ws, size_t ws_size,
                              hipStream_t stream) {
    const float* x = (const float*)d_in[0];
    const float* w = (const float*)d_in[1];
    float* g = (float*)d_out;
    double* acc = (double*)d_ws;
    int* ticket = (int*)((char*)d_ws + 8);

    hipMemsetAsync(d_ws, 0, 16, stream);
    k_fused<<<dim3(NBLK), dim3(TPB), 0, stream>>>(x, w, g, acc, ticket, g + GSZ);
}